// Round 1
// baseline (1299.022 us; speedup 1.0000x reference)
//
#include <hip/hip_runtime.h>
#include <stdint.h>

using f32x4  = __attribute__((ext_vector_type(4))) float;
using bf16x8 = __attribute__((ext_vector_type(8))) __bf16;

// ---------------------------------------------------------------------------
// x (fp32) -> bf16 activations
// ---------------------------------------------------------------------------
__global__ void cvt_x_kernel(const float* __restrict__ x, __bf16* __restrict__ out) {
    const int t = blockIdx.x * blockDim.x + threadIdx.x;
    const size_t base = (size_t)t * 8;
    const float4 a = *(const float4*)(x + base);
    const float4 b = *(const float4*)(x + base + 4);
    bf16x8 pv;
    pv[0] = (__bf16)a.x; pv[1] = (__bf16)a.y; pv[2] = (__bf16)a.z; pv[3] = (__bf16)a.w;
    pv[4] = (__bf16)b.x; pv[5] = (__bf16)b.y; pv[6] = (__bf16)b.z; pv[7] = (__bf16)b.w;
    *(bf16x8*)(out + base) = pv;
}

// ---------------------------------------------------------------------------
// Build Bt[o][k] bf16 panel: k = r*I + i -> W[r][o][i]; rows RI..RI+8 = bias;
// rows RI+9..KEXT-1 = 0.   KEXT = RI + 64.
// ---------------------------------------------------------------------------
template<int I, int O>
__global__ void prep_w_kernel(const float* __restrict__ W, const float* __restrict__ b,
                              __bf16* __restrict__ Bt) {
    constexpr int RI = 9 * I;
    constexpr int KEXT = RI + 64;
    const int o  = blockIdx.y;
    const int kc = blockIdx.x * blockDim.x + threadIdx.x;
    if (kc >= (KEXT >> 3)) return;
    const int k0 = kc << 3;
    bf16x8 pv;
#pragma unroll
    for (int q = 0; q < 8; ++q) {
        const int k = k0 + q;
        float v;
        if (k < RI) {
            const int r = k / I;          // I is pow2 -> shift
            const int i = k & (I - 1);
            v = W[((size_t)r * O + o) * I + i];
        } else if (k - RI < 9) {
            v = b[(size_t)(k - RI) * O + o];
        } else {
            v = 0.f;
        }
        pv[q] = (__bf16)v;
    }
    *(bf16x8*)(Bt + (size_t)o * KEXT + k0) = pv;
}

// ---------------------------------------------------------------------------
// Fused relation-mixed GEMM:
//   Out[n,o] = act( sum_k u[n,k] * Bt[o,k] ),  u[n, r*I+i] = E[n,r]*A[n,i],
//   u[n, RI+r] = E[n,r] (bias rows), zero-padded to KEXT.
// 128x128 tile, BK=64, 256 threads (4 waves), mfma_f32_16x16x32_bf16.
// LDS tiles [128 rows][64 k] bf16 with XOR chunk swizzle (T2):
//   byte(row, c) = row*128 + (c ^ ((row&7)<<4))   for 16B chunks.
// B staged by global_load_lds (linear LDS dest, pre-swizzled global source);
// A reg-staged with on-the-fly e-scale (r uniform per K-block since 64|I).
// ---------------------------------------------------------------------------
template<int I, int O, bool RELU, bool OUTF32>
__global__ __launch_bounds__(256, 2)
void kg_gemm(const __bf16* __restrict__ A, const float* __restrict__ E,
             const __bf16* __restrict__ Bt, void* __restrict__ Outv) {
    constexpr int RI   = 9 * I;
    constexpr int KEXT = RI + 64;
    constexpr int NKK  = I >> 6;       // K-blocks per relation segment
    constexpr int NBN  = O >> 7;       // column blocks
    static_assert((I & 63) == 0 && (O & 127) == 0, "tile divisibility");

    __shared__ __align__(16) char lds[32768];
    char* const ldsA = lds;
    char* const ldsB = lds + 16384;

    const int tid  = threadIdx.x;
    const int bid  = blockIdx.x;
    const int bm0  = (bid / NBN) << 7;
    const int bn0  = (bid % NBN) << 7;
    const int lane = tid & 63;
    const int wid  = tid >> 6;
    const int wr   = (wid >> 1) << 6;      // wave row base: 0 or 64
    const int wc   = (wid & 1) << 6;       // wave col base: 0 or 64
    const int l15  = lane & 15;
    const int lk16 = (lane >> 4) << 4;     // fragment k-chunk byte base

    // staging coordinates: chunk c = it*256 + tid -> row = c>>3, chunk byte = (c&7)*16
    int srow[4], sj16[4];
#pragma unroll
    for (int it = 0; it < 4; ++it) {
        const int c = it * 256 + tid;
        srow[it] = c >> 3;
        sj16[it] = (c & 7) << 4;
    }

    f32x4 acc[4][4];
#pragma unroll
    for (int m = 0; m < 4; ++m)
#pragma unroll
        for (int n = 0; n < 4; ++n)
            acc[m][n] = f32x4{0.f, 0.f, 0.f, 0.f};

    auto stageB = [&](int k0) {
#pragma unroll
        for (int it = 0; it < 4; ++it) {
            const int row = srow[it];
            const int js  = sj16[it] ^ ((row & 7) << 4);   // swizzled source chunk (bytes)
            const __bf16* src = Bt + (size_t)(bn0 + row) * KEXT + k0 + (js >> 1);
            __builtin_amdgcn_global_load_lds(
                (const __attribute__((address_space(1))) void*)src,
                (__attribute__((address_space(3))) void*)(ldsB + it * 4096 + tid * 16),
                16, 0, 0);
        }
    };

    auto compute = [&]() {
#pragma unroll
        for (int ks = 0; ks < 2; ++ks) {
            bf16x8 av[4], bv[4];
#pragma unroll
            for (int m = 0; m < 4; ++m) {
                const int row = wr + m * 16 + l15;
                const int off = row * 128 + ((ks * 64 + lk16) ^ ((row & 7) << 4));
                av[m] = *(const bf16x8*)(ldsA + off);
            }
#pragma unroll
            for (int n = 0; n < 4; ++n) {
                const int row = wc + n * 16 + l15;
                const int off = row * 128 + ((ks * 64 + lk16) ^ ((row & 7) << 4));
                bv[n] = *(const bf16x8*)(ldsB + off);
            }
#pragma unroll
            for (int m = 0; m < 4; ++m)
#pragma unroll
                for (int n = 0; n < 4; ++n)
                    acc[m][n] = __builtin_amdgcn_mfma_f32_16x16x32_bf16(
                        av[m], bv[n], acc[m][n], 0, 0, 0);
        }
    };

    int kb = 0;
#pragma unroll 1
    for (int r = 0; r < 9; ++r) {
        float ev[4];
#pragma unroll
        for (int it = 0; it < 4; ++it)
            ev[it] = E[(size_t)(bm0 + srow[it]) * 9 + r];
#pragma unroll 1
        for (int kk = 0; kk < NKK; ++kk, ++kb) {
            const int k0 = kb << 6;
            stageB(k0);
#pragma unroll
            for (int it = 0; it < 4; ++it) {
                const int row = srow[it];
                const size_t gr = (size_t)(bm0 + row);
                const bf16x8 v = *(const bf16x8*)(A + gr * I + (kk << 6) + (sj16[it] >> 1));
                bf16x8 pv;
#pragma unroll
                for (int q = 0; q < 8; ++q)
                    pv[q] = (__bf16)((float)v[q] * ev[it]);
                *(bf16x8*)(ldsA + row * 128 + (sj16[it] ^ ((row & 7) << 4))) = pv;
            }
            __syncthreads();
            compute();
            __syncthreads();
        }
    }
    // bias K-block (k0 == RI): u[n, RI+q] = E[n,q] for q<9 else 0
    {
        stageB(RI);
#pragma unroll
        for (int it = 0; it < 4; ++it) {
            const int row = srow[it];
            const size_t gr = (size_t)(bm0 + row);
            bf16x8 pv;
#pragma unroll
            for (int q = 0; q < 8; ++q) {
                const int kl = (sj16[it] >> 1) + q;
                pv[q] = (kl < 9) ? (__bf16)E[gr * 9 + kl] : (__bf16)0.f;
            }
            *(bf16x8*)(ldsA + row * 128 + (sj16[it] ^ ((row & 7) << 4))) = pv;
        }
        __syncthreads();
        compute();
    }

    // epilogue: C/D layout col = lane&15, row = (lane>>4)*4 + reg
    const int orow0 = bm0 + wr + (lane >> 4) * 4;
    const int ocol0 = bn0 + wc + l15;
#pragma unroll
    for (int m = 0; m < 4; ++m) {
#pragma unroll
        for (int n = 0; n < 4; ++n) {
#pragma unroll
            for (int jj = 0; jj < 4; ++jj) {
                float v = acc[m][n][jj];
                if (RELU) v = fmaxf(v, 0.f);
                const size_t idx = (size_t)(orow0 + m * 16 + jj) * O + (ocol0 + n * 16);
                if (OUTF32) ((float*)Outv)[idx] = v;
                else        ((__bf16*)Outv)[idx] = (__bf16)v;
            }
        }
    }
}

// ---------------------------------------------------------------------------
extern "C" void kernel_launch(void* const* d_in, const int* in_sizes, int n_in,
                              void* d_out, int out_size, void* d_ws, size_t ws_size,
                              hipStream_t stream) {
    const float* x  = (const float*)d_in[0];
    const float* E  = (const float*)d_in[1];
    const float* W0 = (const float*)d_in[2];
    const float* b0 = (const float*)d_in[3];
    const float* W1 = (const float*)d_in[4];
    const float* b1 = (const float*)d_in[5];
    const float* W2 = (const float*)d_in[6];
    const float* b2 = (const float*)d_in[7];
    const float* W3 = (const float*)d_in[8];
    const float* b3 = (const float*)d_in[9];

    char* ws = (char*)d_ws;
    const size_t actBytes = (size_t)65536 * 512 * 2;           // 64 MiB each
    __bf16* actA = (__bf16*)ws;
    __bf16* actB = (__bf16*)(ws + actBytes);
    char* p = ws + 2 * actBytes;
    __bf16* Bt0 = (__bf16*)p; p += (size_t)512 * 2368 * 2;
    __bf16* Bt1 = (__bf16*)p; p += (size_t)512 * 4672 * 2;
    __bf16* Bt2 = (__bf16*)p; p += (size_t)512 * 4672 * 2;
    __bf16* Bt3 = (__bf16*)p; p += (size_t)256 * 4672 * 2;
    if (ws_size < (size_t)(p - ws)) return;   // ws too small -> visible failure

    // prep
    cvt_x_kernel<<<dim3(8192), dim3(256), 0, stream>>>(x, actA);
    prep_w_kernel<256, 512><<<dim3(2, 512), dim3(256), 0, stream>>>(W0, b0, Bt0);
    prep_w_kernel<512, 512><<<dim3(3, 512), dim3(256), 0, stream>>>(W1, b1, Bt1);
    prep_w_kernel<512, 512><<<dim3(3, 512), dim3(256), 0, stream>>>(W2, b2, Bt2);
    prep_w_kernel<512, 256><<<dim3(3, 256), dim3(256), 0, stream>>>(W3, b3, Bt3);

    // 4 fused layers
    kg_gemm<256, 512, true,  false><<<dim3(512 * 4), dim3(256), 0, stream>>>(actA, E, Bt0, actB);
    kg_gemm<512, 512, true,  false><<<dim3(512 * 4), dim3(256), 0, stream>>>(actB, E, Bt1, actA);
    kg_gemm<512, 512, true,  false><<<dim3(512 * 4), dim3(256), 0, stream>>>(actA, E, Bt2, actB);
    kg_gemm<512, 256, false, true ><<<dim3(512 * 2), dim3(256), 0, stream>>>(actB, E, Bt3, d_out);
}

// Round 2
// 937.575 us; speedup vs baseline: 1.3855x; 1.3855x over previous
//
#include <hip/hip_runtime.h>
#include <stdint.h>

using f32x4  = __attribute__((ext_vector_type(4))) float;
using bf16x8 = __attribute__((ext_vector_type(8))) __bf16;

// ---------------------------------------------------------------------------
// x (fp32) -> bf16 activations
// ---------------------------------------------------------------------------
__global__ void cvt_x_kernel(const float* __restrict__ x, __bf16* __restrict__ out) {
    const int t = blockIdx.x * blockDim.x + threadIdx.x;
    const size_t base = (size_t)t * 8;
    const float4 a = *(const float4*)(x + base);
    const float4 b = *(const float4*)(x + base + 4);
    bf16x8 pv;
    pv[0] = (__bf16)a.x; pv[1] = (__bf16)a.y; pv[2] = (__bf16)a.z; pv[3] = (__bf16)a.w;
    pv[4] = (__bf16)b.x; pv[5] = (__bf16)b.y; pv[6] = (__bf16)b.z; pv[7] = (__bf16)b.w;
    *(bf16x8*)(out + base) = pv;
}

// ---------------------------------------------------------------------------
// Build Bt[o][k] bf16 panel: k = r*I + i -> W[r][o][i]; rows RI..RI+8 = bias;
// rows RI+9..KEXT-1 = 0.   KEXT = RI + 64.
// ---------------------------------------------------------------------------
template<int I, int O>
__global__ void prep_w_kernel(const float* __restrict__ W, const float* __restrict__ b,
                              __bf16* __restrict__ Bt) {
    constexpr int RI = 9 * I;
    constexpr int KEXT = RI + 64;
    const int o  = blockIdx.y;
    const int kc = blockIdx.x * blockDim.x + threadIdx.x;
    if (kc >= (KEXT >> 3)) return;
    const int k0 = kc << 3;
    bf16x8 pv;
#pragma unroll
    for (int q = 0; q < 8; ++q) {
        const int k = k0 + q;
        float v;
        if (k < RI) {
            const int r = k / I;
            const int i = k & (I - 1);
            v = W[((size_t)r * O + o) * I + i];
        } else if (k - RI < 9) {
            v = b[(size_t)(k - RI) * O + o];
        } else {
            v = 0.f;
        }
        pv[q] = (__bf16)v;
    }
    *(bf16x8*)(Bt + (size_t)o * KEXT + k0) = pv;
}

// ---------------------------------------------------------------------------
// Relation-mixed GEMM via accumulator folding:
//   y[n,o] = sum_r e[n,r] * ( sum_i x[n,i] W[r,o,i] )  + sum_r e[n,r] b[r,o]
// K order: i-chunk (128) OUTER, r INNER. A chunk staged UNSCALED once per
// chunk (global_load_lds, pre-swizzled source, T2 XOR swizzle); per r only B
// is staged; MFMA accumulates into acc2 (zero-init via C-in=0), then
// acc += e_r (fp32, LDS-resident Et) * acc2.  Bias = one extra K-step where
// A-cols = e (bf16) and B-rows = b, accumulated directly into acc.
// 128x128 tile, 4 waves, mfma_f32_16x16x32_bf16.
// ---------------------------------------------------------------------------
template<int I, int O, bool RELU, bool OUTF32>
__global__ __launch_bounds__(256, 2)
void kg_gemm(const __bf16* __restrict__ A, const float* __restrict__ E,
             const __bf16* __restrict__ Bt, void* __restrict__ Outv) {
    constexpr int RI   = 9 * I;
    constexpr int KEXT = RI + 64;
    constexpr int NCH  = I >> 7;       // 128-wide i-chunks
    constexpr int NBN  = O >> 7;       // column blocks
    static_assert((I & 127) == 0 && (O & 127) == 0, "tile divisibility");

    __shared__ __align__(16) char lds[32768 * 2 + 4608];
    char* const ldsA  = lds;
    char* const ldsB  = lds + 32768;
    float* const ldsE = (float*)(lds + 65536);   // Et[r][row], r<9, row<128

    const int tid  = threadIdx.x;
    const int nwg  = gridDim.x;
    const int braw = blockIdx.x;
    // m204 bijective XCD swizzle (grids here are multiples of 8)
    const int bid  = (braw & 7) * (nwg >> 3) + (braw >> 3);
    const int bm0  = (bid / NBN) << 7;
    const int bn0  = (bid % NBN) << 7;
    const int lane = tid & 63;
    const int wid  = tid >> 6;
    const int wr   = (wid >> 1) << 6;      // wave row base: 0 or 64
    const int wc   = (wid & 1) << 6;       // wave col base: 0 or 64
    const int l15  = lane & 15;
    const int lq   = lane >> 4;

    // stage Et[r][row] (fp32) once
    if (tid < 128) {
        const float* e = E + (size_t)(bm0 + tid) * 9;
#pragma unroll
        for (int q = 0; q < 9; ++q) ldsE[q * 128 + tid] = e[q];
    }

    // loop-invariant fragment LDS byte offsets (row stride 256 B, 16 chunks/row)
    int aoff[4][4], boff[4][4];
#pragma unroll
    for (int m = 0; m < 4; ++m) {
        const int ra = wr + m * 16 + l15;
        const int rb = wc + m * 16 + l15;
#pragma unroll
        for (int ks = 0; ks < 4; ++ks) {
            aoff[m][ks] = ra * 256 + ((((ks << 2) + lq) ^ (ra & 7)) << 4);
            boff[m][ks] = rb * 256 + ((((ks << 2) + lq) ^ (rb & 7)) << 4);
        }
    }

    f32x4 acc[4][4];
#pragma unroll
    for (int m = 0; m < 4; ++m)
#pragma unroll
        for (int n = 0; n < 4; ++n)
            acc[m][n] = f32x4{0.f, 0.f, 0.f, 0.f};
    const f32x4 zero4 = {0.f, 0.f, 0.f, 0.f};

    // 128 rows x 128 cols bf16 = 2048 16B-chunks; linear LDS dest, swizzled src
    auto stageA = [&](int c) {
#pragma unroll
        for (int rr = 0; rr < 8; ++rr) {
            const int q    = rr * 256 + tid;
            const int row  = q >> 4;
            const int jsrc = (q & 15) ^ (row & 7);
            const __bf16* src = A + (size_t)(bm0 + row) * I + (c << 7) + (jsrc << 3);
            __builtin_amdgcn_global_load_lds(
                (const __attribute__((address_space(1))) void*)src,
                (__attribute__((address_space(3))) void*)(ldsA + q * 16), 16, 0, 0);
        }
    };
    auto stageB = [&](int c, int r) {
#pragma unroll
        for (int rr = 0; rr < 8; ++rr) {
            const int q    = rr * 256 + tid;
            const int row  = q >> 4;
            const int jsrc = (q & 15) ^ (row & 7);
            const __bf16* src = Bt + (size_t)(bn0 + row) * KEXT + r * I + (c << 7) + (jsrc << 3);
            __builtin_amdgcn_global_load_lds(
                (const __attribute__((address_space(1))) void*)src,
                (__attribute__((address_space(3))) void*)(ldsB + q * 16), 16, 0, 0);
        }
    };

#pragma unroll 1
    for (int c = 0; c < NCH; ++c) {
        stageA(c);
#pragma unroll 1
        for (int r = 0; r < 9; ++r) {
            stageB(c, r);
            __syncthreads();
            f32x4 acc2[4][4];
#pragma unroll
            for (int ks = 0; ks < 4; ++ks) {
                bf16x8 av[4], bv[4];
#pragma unroll
                for (int m = 0; m < 4; ++m) av[m] = *(const bf16x8*)(ldsA + aoff[m][ks]);
#pragma unroll
                for (int n = 0; n < 4; ++n) bv[n] = *(const bf16x8*)(ldsB + boff[n][ks]);
#pragma unroll
                for (int m = 0; m < 4; ++m)
#pragma unroll
                    for (int n = 0; n < 4; ++n)
                        acc2[m][n] = __builtin_amdgcn_mfma_f32_16x16x32_bf16(
                            av[m], bv[n], (ks == 0) ? zero4 : acc2[m][n], 0, 0, 0);
            }
            // fold: acc += e[row][r] * acc2   (e fp32 from LDS, rows j=0..3 contiguous)
#pragma unroll
            for (int m = 0; m < 4; ++m) {
                const f32x4 ev = *(const f32x4*)(ldsE + r * 128 + wr + m * 16 + lq * 4);
#pragma unroll
                for (int n = 0; n < 4; ++n)
#pragma unroll
                    for (int j = 0; j < 4; ++j)
                        acc[m][n][j] += ev[j] * acc2[m][n][j];
            }
            __syncthreads();
        }
    }

    // ---- bias K-step: A-cols = e (bf16), B-rows = b (at k0 = RI, zero-padded)
    {
        // stage B bias chunk: 128 rows x 64 cols, row stride 128 B (8 chunks/row)
#pragma unroll
        for (int rr = 0; rr < 4; ++rr) {
            const int q    = rr * 256 + tid;
            const int row  = q >> 3;
            const int jsrc = (q & 7) ^ (row & 7);
            const __bf16* src = Bt + (size_t)(bn0 + row) * KEXT + RI + (jsrc << 3);
            __builtin_amdgcn_global_load_lds(
                (const __attribute__((address_space(1))) void*)src,
                (__attribute__((address_space(3))) void*)(ldsB + q * 16), 16, 0, 0);
        }
        // build A bias tile from ldsE (reg-staged, swizzled dest is fine here)
#pragma unroll
        for (int rr = 0; rr < 4; ++rr) {
            const int q   = rr * 256 + tid;
            const int row = q >> 3;
            const int j   = q & 7;
            bf16x8 pv;
#pragma unroll
            for (int e8 = 0; e8 < 8; ++e8) {
                const int kl = j * 8 + e8;
                pv[e8] = (kl < 9) ? (__bf16)ldsE[kl * 128 + row] : (__bf16)0.f;
            }
            *(bf16x8*)(ldsA + row * 128 + (((j ^ (row & 7))) << 4)) = pv;
        }
        __syncthreads();
#pragma unroll
        for (int ks = 0; ks < 2; ++ks) {
            bf16x8 av[4], bv[4];
#pragma unroll
            for (int m = 0; m < 4; ++m) {
                const int ra = wr + m * 16 + l15;
                av[m] = *(const bf16x8*)(ldsA + ra * 128 + ((((ks << 2) + lq) ^ (ra & 7)) << 4));
            }
#pragma unroll
            for (int n = 0; n < 4; ++n) {
                const int rb = wc + n * 16 + l15;
                bv[n] = *(const bf16x8*)(ldsB + rb * 128 + ((((ks << 2) + lq) ^ (rb & 7)) << 4));
            }
#pragma unroll
            for (int m = 0; m < 4; ++m)
#pragma unroll
                for (int n = 0; n < 4; ++n)
                    acc[m][n] = __builtin_amdgcn_mfma_f32_16x16x32_bf16(
                        av[m], bv[n], acc[m][n], 0, 0, 0);
        }
    }

    // epilogue: C/D layout col = lane&15, row = (lane>>4)*4 + reg
    const int orow0 = bm0 + wr + lq * 4;
    const int ocol0 = bn0 + wc + l15;
#pragma unroll
    for (int m = 0; m < 4; ++m) {
#pragma unroll
        for (int n = 0; n < 4; ++n) {
#pragma unroll
            for (int jj = 0; jj < 4; ++jj) {
                float v = acc[m][n][jj];
                if (RELU) v = fmaxf(v, 0.f);
                const size_t idx = (size_t)(orow0 + m * 16 + jj) * O + (ocol0 + n * 16);
                if (OUTF32) ((float*)Outv)[idx] = v;
                else        ((__bf16*)Outv)[idx] = (__bf16)v;
            }
        }
    }
}

// ---------------------------------------------------------------------------
extern "C" void kernel_launch(void* const* d_in, const int* in_sizes, int n_in,
                              void* d_out, int out_size, void* d_ws, size_t ws_size,
                              hipStream_t stream) {
    const float* x  = (const float*)d_in[0];
    const float* E  = (const float*)d_in[1];
    const float* W0 = (const float*)d_in[2];
    const float* b0 = (const float*)d_in[3];
    const float* W1 = (const float*)d_in[4];
    const float* b1 = (const float*)d_in[5];
    const float* W2 = (const float*)d_in[6];
    const float* b2 = (const float*)d_in[7];
    const float* W3 = (const float*)d_in[8];
    const float* b3 = (const float*)d_in[9];

    char* ws = (char*)d_ws;
    const size_t actBytes = (size_t)65536 * 512 * 2;           // 64 MiB each
    __bf16* actA = (__bf16*)ws;
    __bf16* actB = (__bf16*)(ws + actBytes);
    char* p = ws + 2 * actBytes;
    __bf16* Bt0 = (__bf16*)p; p += (size_t)512 * 2368 * 2;
    __bf16* Bt1 = (__bf16*)p; p += (size_t)512 * 4672 * 2;
    __bf16* Bt2 = (__bf16*)p; p += (size_t)512 * 4672 * 2;
    __bf16* Bt3 = (__bf16*)p; p += (size_t)256 * 4672 * 2;
    if (ws_size < (size_t)(p - ws)) return;   // ws too small -> visible failure

    // prep
    cvt_x_kernel<<<dim3(8192), dim3(256), 0, stream>>>(x, actA);
    prep_w_kernel<256, 512><<<dim3(2, 512), dim3(256), 0, stream>>>(W0, b0, Bt0);
    prep_w_kernel<512, 512><<<dim3(3, 512), dim3(256), 0, stream>>>(W1, b1, Bt1);
    prep_w_kernel<512, 512><<<dim3(3, 512), dim3(256), 0, stream>>>(W2, b2, Bt2);
    prep_w_kernel<512, 256><<<dim3(3, 256), dim3(256), 0, stream>>>(W3, b3, Bt3);

    // 4 fused layers
    kg_gemm<256, 512, true,  false><<<dim3(512 * 4), dim3(256), 0, stream>>>(actA, E, Bt0, actB);
    kg_gemm<512, 512, true,  false><<<dim3(512 * 4), dim3(256), 0, stream>>>(actB, E, Bt1, actA);
    kg_gemm<512, 512, true,  false><<<dim3(512 * 4), dim3(256), 0, stream>>>(actA, E, Bt2, actB);
    kg_gemm<512, 256, false, true ><<<dim3(512 * 2), dim3(256), 0, stream>>>(actB, E, Bt3, d_out);
}